// Round 3
// baseline (1442.268 us; speedup 1.0000x reference)
//
#include <hip/hip_runtime.h>
#include <cstdint>

#define NSUB 8
#define KC   1024
#define KP   1025
#define KPAD 1028      // padded row length (16B-aligned float4 rows)
#define EDIM 64
#define BTOT 16384
#define DHID 512
#define NDEPTH 4
#define MARGIN 1e-3f   // fp32 top-2 gap below which we re-resolve via np-key emulation

// ---- workspace layout (floats) ----
#define OFF_EMBT 0u                      // [8][64][1028], pre-scaled by -2
#define OFF_ESQ  526336u                 // [8][1028]
#define OFF_G2   534560u                 // [8][1025][1028] = 2*<e_c,e_k>
#define OFF_PART 8964160u                // [16384] per-wave loss partials

// ---- output layout (floats, concatenated in return order) ----
#define O_LOSS 0
#define O_ZQ   1ull
#define O_PERP 8388609ull
#define O_ENC  8388610ull
#define O_IDX  142737410ull

// numpy SSE2 pairwise sum of 64 fp32 squares: r[j] = left-fold of a[8t+j],
// u[j] = r[j]+r[j+4], res = (u0+u1)+(u2+u3). Bit-matches np.sum(x*x, axis=-1).
__device__ __forceinline__ float np_pairwise_sq64(const float* a) {
    float r[8];
    #pragma unroll
    for (int j = 0; j < 8; ++j) r[j] = __fmul_rn(a[j], a[j]);
    #pragma unroll
    for (int t = 1; t < 8; ++t)
        #pragma unroll
        for (int j = 0; j < 8; ++j)
            r[j] = __fadd_rn(r[j], __fmul_rn(a[8 * t + j], a[8 * t + j]));
    float u0 = __fadd_rn(r[0], r[4]), u1 = __fadd_rn(r[1], r[5]);
    float u2 = __fadd_rn(r[2], r[6]), u3 = __fadd_rn(r[3], r[7]);
    return __fadd_rn(__fadd_rn(u0, u1), __fadd_rn(u2, u3));
}

// Build embT[n][e][k] = -2*emb[n][k-1][e] (pad row k=0 and cols>1024 are 0)
// and e_sq[n][k] = np-pairwise sum of emb^2 (bit-matching numpy).
__global__ void prep_embT(const float* __restrict__ emb, float* __restrict__ ws) {
    int t = blockIdx.x * 256 + threadIdx.x;
    if (t >= NSUB * KPAD) return;
    int n = t / KPAD, k = t - n * KPAD;
    float* embT = ws + OFF_EMBT + (size_t)n * EDIM * KPAD;
    float es = 0.f;
    if (k >= 1 && k <= KC) {
        const float* row = emb + ((size_t)n * KC + (k - 1)) * EDIM;
        float a[EDIM];
        for (int e = 0; e < EDIM; ++e) {
            a[e] = row[e];
            embT[(size_t)e * KPAD + k] = -2.f * a[e];   // exact (exponent shift)
        }
        es = np_pairwise_sq64(a);
    } else {
        for (int e = 0; e < EDIM; ++e) embT[(size_t)e * KPAD + k] = 0.f;
    }
    ws[OFF_ESQ + (size_t)n * KPAD + k] = es;
}

// G2[n][c][k] = 2*<e_c, e_k> (pad-aware). Fast-path only (precision uncritical).
__global__ void prep_G(const float* __restrict__ emb, float* __restrict__ ws) {
    __shared__ float A[32][EDIM];
    int n  = blockIdx.x & 7;
    int c0 = (blockIdx.x >> 3) * 32;
    for (int idx = threadIdx.x; idx < 32 * EDIM; idx += 256) {
        int ci = idx >> 6, e = idx & 63, c = c0 + ci;
        float v = 0.f;
        if (c >= 1 && c <= KC) v = emb[((size_t)n * KC + (c - 1)) * EDIM + e];
        A[ci][e] = v;
    }
    __syncthreads();
    float* G2 = ws + OFF_G2 + (size_t)n * KP * KPAD;
    for (int k = threadIdx.x; k <= KC; k += 256) {
        float4 B4[16];
        if (k >= 1) {
            const float4* row = (const float4*)(emb + ((size_t)n * KC + (k - 1)) * EDIM);
            #pragma unroll
            for (int q = 0; q < 16; ++q) B4[q] = row[q];
        } else {
            #pragma unroll
            for (int q = 0; q < 16; ++q) B4[q] = make_float4(0.f, 0.f, 0.f, 0.f);
        }
        for (int ci = 0; ci < 32; ++ci) {
            int c = c0 + ci;
            if (c > KC) break;
            float s = 0.f;
            #pragma unroll
            for (int q = 0; q < 16; ++q) {
                s = fmaf(A[ci][4 * q + 0], B4[q].x, s);
                s = fmaf(A[ci][4 * q + 1], B4[q].y, s);
                s = fmaf(A[ci][4 * q + 2], B4[q].z, s);
                s = fmaf(A[ci][4 * q + 3], B4[q].w, s);
            }
            G2[(size_t)c * KPAD + k] = s + s;
        }
    }
}

// Main fused kernel: block = 256 thr = 4 waves; wave handles 8 b's for one n.
__global__ void __launch_bounds__(256, 2) vq_main(
    const float* __restrict__ z, const float* __restrict__ emb,
    float* __restrict__ ws, float* __restrict__ out)
{
    __shared__ __align__(16) float zt[32][EDIM];
    __shared__ __align__(16) float eT[8 * KPAD];
    __shared__ float zres_sh[4][EDIM];     // per-wave residual for fallback

    const int n    = blockIdx.x & 7;
    const int b0   = (blockIdx.x >> 3) << 5;   // 32 b's per block
    const int w    = threadIdx.x >> 6;
    const int lane = threadIdx.x & 63;

    for (int idx = threadIdx.x; idx < 32 * EDIM; idx += 256) {
        int i = idx >> 6, e = idx & 63;
        zt[i][e] = z[(size_t)(b0 + i) * DHID + n * EDIM + e];
    }

    const float* __restrict__ esq = ws + OFF_ESQ + (size_t)n * KPAD;
    float4 acc[8][4];
    float s1024[8], zq[8], zres_f[8];
    {
        float4 e4[4];
        #pragma unroll
        for (int j = 0; j < 4; ++j)
            e4[j] = *(const float4*)(esq + j * 256 + 4 * lane);
        float es24 = esq[KC];
        #pragma unroll
        for (int i = 0; i < 8; ++i) {
            #pragma unroll
            for (int j = 0; j < 4; ++j) acc[i][j] = e4[j];
            s1024[i] = es24;
            zq[i] = 0.f;
        }
    }

    // depth-0: score_k = e_sq[k] + sum_e z[e] * (-2*emb[e][k])
    const float* __restrict__ embTn = ws + OFF_EMBT + (size_t)n * EDIM * KPAD;
    for (int ec = 0; ec < EDIM; ec += 8) {
        __syncthreads();
        {
            const float4* src = (const float4*)(embTn + (size_t)ec * KPAD);
            float4* dst = (float4*)eT;
            for (int idx = threadIdx.x; idx < 8 * KPAD / 4; idx += 256)
                dst[idx] = src[idx];
        }
        __syncthreads();
        #pragma unroll
        for (int e8 = 0; e8 < 8; ++e8) {
            float zb[8];
            #pragma unroll
            for (int i = 0; i < 8; ++i) zb[i] = zt[(w << 3) + i][ec + e8];
            float ev24 = eT[e8 * KPAD + KC];
            #pragma unroll
            for (int j = 0; j < 4; ++j) {
                float4 ev = *(const float4*)(eT + e8 * KPAD + j * 256 + 4 * lane);
                #pragma unroll
                for (int i = 0; i < 8; ++i) {
                    acc[i][j].x = fmaf(zb[i], ev.x, acc[i][j].x);
                    acc[i][j].y = fmaf(zb[i], ev.y, acc[i][j].y);
                    acc[i][j].z = fmaf(zb[i], ev.z, acc[i][j].z);
                    acc[i][j].w = fmaf(zb[i], ev.w, acc[i][j].w);
                }
            }
            #pragma unroll
            for (int i = 0; i < 8; ++i) s1024[i] = fmaf(zb[i], ev24, s1024[i]);
        }
    }

    #pragma unroll
    for (int i = 0; i < 8; ++i) zres_f[i] = zt[(w << 3) + i][lane];

    const float* __restrict__ G2n = ws + OFF_G2 + (size_t)n * KP * KPAD;
    int idxf[8];
    for (int d = 0; d < NDEPTH; ++d) {
        #pragma unroll
        for (int i = 0; i < 8; ++i) {
            float bv = 3.402823466e38f, bv2 = 3.402823466e38f;
            int bk = 0;
            #pragma unroll
            for (int j = 0; j < 4; ++j) {
                int kb = j * 256 + (lane << 2);
                float4 a = acc[i][j];
                if (a.x < bv)      { bv2 = bv; bv = a.x; bk = kb; }
                else if (a.x < bv2){ bv2 = a.x; }
                if (a.y < bv)      { bv2 = bv; bv = a.y; bk = kb + 1; }
                else if (a.y < bv2){ bv2 = a.y; }
                if (a.z < bv)      { bv2 = bv; bv = a.z; bk = kb + 2; }
                else if (a.z < bv2){ bv2 = a.z; }
                if (a.w < bv)      { bv2 = bv; bv = a.w; bk = kb + 3; }
                else if (a.w < bv2){ bv2 = a.w; }
            }
            if (s1024[i] < bv)      { bv2 = bv; bv = s1024[i]; bk = KC; }
            else if (s1024[i] < bv2){ bv2 = s1024[i]; }
            #pragma unroll
            for (int off = 32; off >= 1; off >>= 1) {
                float ov  = __shfl_xor(bv, off, 64);
                int   ok  = __shfl_xor(bk, off, 64);
                float ov2 = __shfl_xor(bv2, off, 64);
                float loser;
                if (ov < bv || (ov == bv && ok < bk)) { loser = bv; bv = ov; bk = ok; }
                else loser = ov;
                bv2 = fminf(fminf(bv2, ov2), loser);
            }
            // near-tie (wave-uniform, rare): emulate numpy's fp32 d2 key exactly.
            // key_k = fl( fl(A32 - fl(2*B32_k)) + esq32_k ), ties -> lowest k.
            if (bv2 - bv < MARGIN) {
                zres_sh[w][lane] = zres_f[i];
                asm volatile("s_waitcnt lgkmcnt(0)" ::: "memory");
                // A32 = numpy pairwise sum of zres^2 (all lanes compute identically)
                float zl[EDIM];
                #pragma unroll
                for (int e = 0; e < EDIM; ++e) zl[e] = zres_sh[w][e];
                float A32 = np_pairwise_sq64(zl);
                float bestk = 3.402823466e38f;
                int bki = 1 << 30;
                for (int j2 = 0; j2 < 17; ++j2) {
                    int k = lane + (j2 << 6);
                    float key;
                    if (k == 0) {
                        key = A32;            // B=0, esq=0 for the pad row
                    } else if (k <= KC) {
                        const float* er = emb + ((size_t)n * KC + (k - 1)) * EDIM;
                        double bd = 0.0;
                        #pragma unroll 8
                        for (int e = 0; e < EDIM; ++e)
                            bd = fma((double)er[e], (double)zl[e], bd);
                        float B32  = (float)bd;                 // ~np einsum result
                        float twoB = __fmul_rn(2.0f, B32);      // exact
                        float T    = __fsub_rn(A32, twoB);
                        key = __fadd_rn(T, esq[k]);
                    } else {
                        key = 3.402823466e38f;
                    }
                    if (key < bestk) { bestk = key; bki = k; }
                }
                #pragma unroll
                for (int off = 32; off >= 1; off >>= 1) {
                    float ov = __shfl_xor(bestk, off, 64);
                    int   ok = __shfl_xor(bki, off, 64);
                    if (ov < bestk || (ov == bestk && ok < bki)) { bestk = ov; bki = ok; }
                }
                bk = bki;
            }
            idxf[i] = bk;
            float q = 0.f;
            if (bk > 0)   // wave-uniform branch
                q = emb[((size_t)n * KC + (bk - 1)) * EDIM + lane];
            zq[i] += q;
            zres_f[i] -= q;            // matches reference's fp32 z_res update
            if (d < NDEPTH - 1) {
                const float* grow = G2n + (size_t)bk * KPAD;
                #pragma unroll
                for (int j = 0; j < 4; ++j) {
                    float4 g = *(const float4*)(grow + j * 256 + 4 * lane);
                    acc[i][j].x += g.x; acc[i][j].y += g.y;
                    acc[i][j].z += g.z; acc[i][j].w += g.w;
                }
                s1024[i] += grow[KC];
            }
        }
    }

    // outputs: z_q_st, loss partial, one-hot, indices
    float lsum = 0.f;
    #pragma unroll
    for (int i = 0; i < 8; ++i) {
        int b = b0 + (w << 3) + i;
        float zv = zt[(w << 3) + i][lane];
        float t = zq[i] - zv;
        __builtin_nontemporal_store(zv + t, &out[O_ZQ + (size_t)b * DHID + n * EDIM + lane]);
        lsum = fmaf(t, t, lsum);
    }
    #pragma unroll
    for (int off = 32; off >= 1; off >>= 1) lsum += __shfl_xor(lsum, off, 64);
    if (lane == 0) ws[OFF_PART + (size_t)blockIdx.x * 4 + w] = lsum;

    #pragma unroll
    for (int i = 0; i < 8; ++i) {
        int b = b0 + (w << 3) + i;
        size_t base = O_ENC + ((size_t)b * NSUB + n) * KP;
        int c = idxf[i];
        #pragma unroll
        for (int j2 = 0; j2 < 17; ++j2) {
            int k = (j2 << 6) + lane;
            if (k < KP)
                __builtin_nontemporal_store((k == c) ? 1.f : 0.f, &out[base + k]);
        }
        if (lane == i) out[O_IDX + (size_t)b * NSUB + n] = (float)c;
    }
}

__global__ void vq_finalize(const float* __restrict__ partials, float* __restrict__ out) {
    __shared__ float sm[256];
    float a = 0.f;
    for (int i = threadIdx.x; i < 16384; i += 256) a += partials[i];
    sm[threadIdx.x] = a;
    __syncthreads();
    for (int s = 128; s > 0; s >>= 1) {
        if ((int)threadIdx.x < s) sm[threadIdx.x] += sm[threadIdx.x + s];
        __syncthreads();
    }
    if (threadIdx.x == 0) {
        float mean = sm[0] / 8388608.f;
        out[O_LOSS] = 1.25f * mean;
        out[O_PERP] = 0.f;
    }
}

extern "C" void kernel_launch(void* const* d_in, const int* in_sizes, int n_in,
                              void* d_out, int out_size, void* d_ws, size_t ws_size,
                              hipStream_t stream) {
    const float* z   = (const float*)d_in[0];
    const float* emb = (const float*)d_in[1];
    float* out = (float*)d_out;
    float* ws  = (float*)d_ws;

    hipLaunchKernelGGL(prep_embT, dim3(33), dim3(256), 0, stream, emb, ws);
    hipLaunchKernelGGL(prep_G, dim3(8 * 33), dim3(256), 0, stream, emb, ws);
    hipLaunchKernelGGL(vq_main, dim3(4096), dim3(256), 0, stream, z, emb, ws, out);
    hipLaunchKernelGGL(vq_finalize, dim3(1), dim3(256), 0, stream, ws + OFF_PART, out);
}

// Round 5
// 1275.499 us; speedup vs baseline: 1.1307x; 1.1307x over previous
//
#include <hip/hip_runtime.h>
#include <cstdint>

#define NSUB 8
#define KC   1024
#define KP   1025
#define KPAD 1028      // padded row length (16B-aligned float4 rows)
#define EDIM 64
#define BTOT 16384
#define DHID 512
#define NDEPTH 4
#define MARGIN 1e-3f   // fp32 top-2 gap below which we re-resolve via np-key emulation

typedef float f32x4 __attribute__((ext_vector_type(4)));

// ---- workspace layout (floats) ----
#define OFF_EMBT 0u                      // [8][64][1028], pre-scaled by -2
#define OFF_ESQ  526336u                 // [8][1028]
#define OFF_G2   534560u                 // [8][1025][1028] = 2*<e_c,e_k>
#define OFF_PART 8964160u                // [16384] per-wave loss partials

// ---- output layout (floats, concatenated in return order) ----
#define O_LOSS 0
#define O_ZQ   1ull
#define O_PERP 8388609ull
#define O_ENC  8388610ull
#define O_IDX  142737410ull

// numpy SSE2 pairwise sum of 64 fp32 squares: r[j] = left-fold of a[8t+j],
// u[j] = r[j]+r[j+4], res = (u0+u1)+(u2+u3). Bit-matches np.sum(x*x, axis=-1).
__device__ __forceinline__ float np_pairwise_sq64(const float* a) {
    float r[8];
    #pragma unroll
    for (int j = 0; j < 8; ++j) r[j] = __fmul_rn(a[j], a[j]);
    #pragma unroll
    for (int t = 1; t < 8; ++t)
        #pragma unroll
        for (int j = 0; j < 8; ++j)
            r[j] = __fadd_rn(r[j], __fmul_rn(a[8 * t + j], a[8 * t + j]));
    float u0 = __fadd_rn(r[0], r[4]), u1 = __fadd_rn(r[1], r[5]);
    float u2 = __fadd_rn(r[2], r[6]), u3 = __fadd_rn(r[3], r[7]);
    return __fadd_rn(__fadd_rn(u0, u1), __fadd_rn(u2, u3));
}

// Build embT[n][e][k] = -2*emb[n][k-1][e] (pad row k=0 and cols>1024 are 0)
// and e_sq[n][k] = np-pairwise sum of emb^2 (bit-matching numpy).
__global__ void prep_embT(const float* __restrict__ emb, float* __restrict__ ws) {
    int t = blockIdx.x * 256 + threadIdx.x;
    if (t >= NSUB * KPAD) return;
    int n = t / KPAD, k = t - n * KPAD;
    float* embT = ws + OFF_EMBT + (size_t)n * EDIM * KPAD;
    float es = 0.f;
    if (k >= 1 && k <= KC) {
        const float* row = emb + ((size_t)n * KC + (k - 1)) * EDIM;
        float a[EDIM];
        #pragma unroll
        for (int e = 0; e < EDIM; ++e) {
            a[e] = row[e];
            embT[(size_t)e * KPAD + k] = -2.f * a[e];   // exact (exponent shift)
        }
        es = np_pairwise_sq64(a);
    } else {
        #pragma unroll
        for (int e = 0; e < EDIM; ++e) embT[(size_t)e * KPAD + k] = 0.f;
    }
    ws[OFF_ESQ + (size_t)n * KPAD + k] = es;
}

// G2[n][c][k] = 2*<e_c, e_k> (pad-aware). Fast-path only (precision uncritical).
__global__ void prep_G(const float* __restrict__ emb, float* __restrict__ ws) {
    __shared__ float A[32][EDIM];
    int n  = blockIdx.x & 7;
    int c0 = (blockIdx.x >> 3) * 32;
    for (int idx = threadIdx.x; idx < 32 * EDIM; idx += 256) {
        int ci = idx >> 6, e = idx & 63, c = c0 + ci;
        float v = 0.f;
        if (c >= 1 && c <= KC) v = emb[((size_t)n * KC + (c - 1)) * EDIM + e];
        A[ci][e] = v;
    }
    __syncthreads();
    float* G2 = ws + OFF_G2 + (size_t)n * KP * KPAD;
    for (int k = threadIdx.x; k <= KC; k += 256) {
        float4 B4[16];
        if (k >= 1) {
            const float4* row = (const float4*)(emb + ((size_t)n * KC + (k - 1)) * EDIM);
            #pragma unroll
            for (int q = 0; q < 16; ++q) B4[q] = row[q];
        } else {
            #pragma unroll
            for (int q = 0; q < 16; ++q) B4[q] = make_float4(0.f, 0.f, 0.f, 0.f);
        }
        for (int ci = 0; ci < 32; ++ci) {
            int c = c0 + ci;
            if (c > KC) break;
            float s = 0.f;
            #pragma unroll
            for (int q = 0; q < 16; ++q) {
                s = fmaf(A[ci][4 * q + 0], B4[q].x, s);
                s = fmaf(A[ci][4 * q + 1], B4[q].y, s);
                s = fmaf(A[ci][4 * q + 2], B4[q].z, s);
                s = fmaf(A[ci][4 * q + 3], B4[q].w, s);
            }
            G2[(size_t)c * KPAD + k] = s + s;
        }
    }
}

// Main fused kernel: block = 256 thr = 4 waves; wave handles 8 b's for one n.
__global__ void __launch_bounds__(256, 2) vq_main(
    const float* __restrict__ z, const float* __restrict__ emb,
    float* __restrict__ ws, float* __restrict__ out)
{
    __shared__ __align__(16) float zt[32][EDIM];
    __shared__ __align__(16) float eT[8 * KPAD];
    __shared__ float zres_sh[4][EDIM];     // per-wave residual for resolve

    const int n    = blockIdx.x & 7;
    const int b0   = (blockIdx.x >> 3) << 5;   // 32 b's per block
    const int w    = threadIdx.x >> 6;
    const int lane = threadIdx.x & 63;

    for (int idx = threadIdx.x; idx < 32 * EDIM; idx += 256) {
        int i = idx >> 6, e = idx & 63;
        zt[i][e] = z[(size_t)(b0 + i) * DHID + n * EDIM + e];
    }

    const float* __restrict__ esq = ws + OFF_ESQ + (size_t)n * KPAD;
    float4 acc[8][4];
    float s1024[8], zq[8], zres_f[8];
    {
        float4 e4[4];
        #pragma unroll
        for (int j = 0; j < 4; ++j)
            e4[j] = *(const float4*)(esq + j * 256 + 4 * lane);
        float es24 = esq[KC];
        #pragma unroll
        for (int i = 0; i < 8; ++i) {
            #pragma unroll
            for (int j = 0; j < 4; ++j) acc[i][j] = e4[j];
            s1024[i] = es24;
            zq[i] = 0.f;
        }
    }

    // depth-0: score_k = e_sq[k] + sum_e z[e] * (-2*emb[e][k])
    const float* __restrict__ embTn = ws + OFF_EMBT + (size_t)n * EDIM * KPAD;
    for (int ec = 0; ec < EDIM; ec += 8) {
        __syncthreads();
        {
            const float4* src = (const float4*)(embTn + (size_t)ec * KPAD);
            float4* dst = (float4*)eT;
            for (int idx = threadIdx.x; idx < 8 * KPAD / 4; idx += 256)
                dst[idx] = src[idx];
        }
        __syncthreads();
        #pragma unroll
        for (int e8 = 0; e8 < 8; ++e8) {
            float zb[8];
            #pragma unroll
            for (int i = 0; i < 8; ++i) zb[i] = zt[(w << 3) + i][ec + e8];
            float ev24 = eT[e8 * KPAD + KC];
            #pragma unroll
            for (int j = 0; j < 4; ++j) {
                float4 ev = *(const float4*)(eT + e8 * KPAD + j * 256 + 4 * lane);
                #pragma unroll
                for (int i = 0; i < 8; ++i) {
                    acc[i][j].x = fmaf(zb[i], ev.x, acc[i][j].x);
                    acc[i][j].y = fmaf(zb[i], ev.y, acc[i][j].y);
                    acc[i][j].z = fmaf(zb[i], ev.z, acc[i][j].z);
                    acc[i][j].w = fmaf(zb[i], ev.w, acc[i][j].w);
                }
            }
            #pragma unroll
            for (int i = 0; i < 8; ++i) s1024[i] = fmaf(zb[i], ev24, s1024[i]);
        }
    }

    #pragma unroll
    for (int i = 0; i < 8; ++i) zres_f[i] = zt[(w << 3) + i][lane];

    const float* __restrict__ G2n = ws + OFF_G2 + (size_t)n * KP * KPAD;
    int idxf[8];
    for (int d = 0; d < NDEPTH; ++d) {
        #pragma unroll
        for (int i = 0; i < 8; ++i) {
            // local scan: min + lowest-index over this lane's 17 slots
            float bv = 3.402823466e38f;
            int bk = 0;
            #pragma unroll
            for (int j = 0; j < 4; ++j) {
                int kb = j * 256 + (lane << 2);
                float4 a = acc[i][j];
                if (a.x < bv) { bv = a.x; bk = kb; }
                if (a.y < bv) { bv = a.y; bk = kb + 1; }
                if (a.z < bv) { bv = a.z; bk = kb + 2; }
                if (a.w < bv) { bv = a.w; bk = kb + 3; }
            }
            if (s1024[i] < bv) { bv = s1024[i]; bk = KC; }
            // wave argmin with lowest-index tie-break (== jnp.argmin)
            #pragma unroll
            for (int off = 32; off >= 1; off >>= 1) {
                float ov = __shfl_xor(bv, off, 64);
                int   ok = __shfl_xor(bk, off, 64);
                if (ov < bv || (ov == bv && ok < bk)) { bv = ov; bk = ok; }
            }
            // candidate mask: all slots within MARGIN of the global min
            float thr = __fadd_rn(bv, MARGIN);
            int m17 = 0;
            #pragma unroll
            for (int j = 0; j < 4; ++j) {
                float4 a = acc[i][j];
                if (a.x < thr) m17 |= 1 << (4 * j + 0);
                if (a.y < thr) m17 |= 1 << (4 * j + 1);
                if (a.z < thr) m17 |= 1 << (4 * j + 2);
                if (a.w < thr) m17 |= 1 << (4 * j + 3);
            }
            if (lane == 0 && s1024[i] < thr) m17 |= 1 << 16;
            unsigned long long lmask = __ballot(m17 != 0);
            bool multi = (__popcll(lmask) > 1) || __any(__popc(m17) > 1);
            // ambiguous (rare, wave-uniform): recheck candidates with numpy's
            // exact fp32 key: key_k = fl(fl(A32 - fl(2*B32_k)) + esq32_k)
            if (multi) {
                zres_sh[w][lane] = zres_f[i];
                asm volatile("s_waitcnt lgkmcnt(0)" ::: "memory");
                float r8[8];
                #pragma unroll
                for (int j = 0; j < 8; ++j)
                    r8[j] = __fmul_rn(zres_sh[w][j], zres_sh[w][j]);
                #pragma unroll
                for (int t2 = 1; t2 < 8; ++t2)
                    #pragma unroll
                    for (int j = 0; j < 8; ++j) {
                        float v = zres_sh[w][8 * t2 + j];
                        r8[j] = __fadd_rn(r8[j], __fmul_rn(v, v));
                    }
                float A32 = __fadd_rn(__fadd_rn(__fadd_rn(r8[0], r8[4]), __fadd_rn(r8[1], r8[5])),
                                      __fadd_rn(__fadd_rn(r8[2], r8[6]), __fadd_rn(r8[3], r8[7])));
                float bestkey = 3.402823466e38f;
                int bkk = 1 << 30;
                unsigned long long mm = lmask;
                while (mm) {
                    int src = __ffsll((unsigned long long)mm) - 1;
                    mm &= mm - 1;
                    int sm = __shfl(m17, src, 64);
                    while (sm) {
                        int bit = __ffs(sm) - 1;
                        sm &= sm - 1;
                        int k = (bit == 16) ? KC : ((bit >> 2) * 256 + (src << 2) + (bit & 3));
                        float key;
                        if (k == 0) {
                            key = A32;
                        } else {
                            // cooperative exact dot: coalesced row load, fp64 butterfly
                            double p = (double)emb[((size_t)n * KC + (k - 1)) * EDIM + lane]
                                     * (double)zres_f[i];
                            #pragma unroll
                            for (int off = 32; off >= 1; off >>= 1)
                                p += __shfl_xor(p, off, 64);
                            float B32  = (float)p;
                            float twoB = __fmul_rn(2.0f, B32);
                            key = __fadd_rn(__fsub_rn(A32, twoB), esq[k]);
                        }
                        if (key < bestkey || (key == bestkey && k < bkk)) {
                            bestkey = key; bkk = k;
                        }
                    }
                }
                bk = bkk;
            }
            idxf[i] = bk;
            float q = 0.f;
            if (bk > 0)   // wave-uniform branch
                q = emb[((size_t)n * KC + (bk - 1)) * EDIM + lane];
            zq[i] += q;
            zres_f[i] -= q;            // matches reference's fp32 z_res update
            if (d < NDEPTH - 1) {
                const float* grow = G2n + (size_t)bk * KPAD;
                #pragma unroll
                for (int j = 0; j < 4; ++j) {
                    float4 g = *(const float4*)(grow + j * 256 + 4 * lane);
                    acc[i][j].x += g.x; acc[i][j].y += g.y;
                    acc[i][j].z += g.z; acc[i][j].w += g.w;
                }
                s1024[i] += grow[KC];
            }
        }
    }

    // outputs: z_q_st, loss partial, indices (one-hot done by onehot_write)
    float lsum = 0.f;
    #pragma unroll
    for (int i = 0; i < 8; ++i) {
        int b = b0 + (w << 3) + i;
        float zv = zt[(w << 3) + i][lane];
        float t = zq[i] - zv;
        __builtin_nontemporal_store(zv + t, &out[O_ZQ + (size_t)b * DHID + n * EDIM + lane]);
        lsum = fmaf(t, t, lsum);
    }
    #pragma unroll
    for (int off = 32; off >= 1; off >>= 1) lsum += __shfl_xor(lsum, off, 64);
    if (lane == 0) ws[OFF_PART + (size_t)blockIdx.x * 4 + w] = lsum;

    #pragma unroll
    for (int i = 0; i < 8; ++i) {
        int b = b0 + (w << 3) + i;
        if (lane == i) out[O_IDX + (size_t)b * NSUB + n] = (float)idxf[i];
    }
}

// Streaming one-hot writer: one wave per (b,n) row; 16B-aligned nt body stores.
__global__ void onehot_write(float* __restrict__ out) {
    int gwave = (blockIdx.x * 256 + threadIdx.x) >> 6;
    int lane  = threadIdx.x & 63;
    if (gwave >= BTOT * NSUB) return;
    int r = gwave;
    int c = (int)out[O_IDX + r];               // written by vq_main earlier in stream
    size_t F = O_ENC + (size_t)r * KP;         // row base (float index)
    int head = (4 - (int)(F & 3)) & 3;
    if (lane < head) out[F + lane] = (lane == c) ? 1.f : 0.f;
    int nbody = KP - head;
    int nb4 = nbody >> 2, tail = nbody & 3;
    f32x4* body = (f32x4*)(out + F + head);
    for (int s = lane; s < nb4; s += 64) {
        int p = head + 4 * s;
        f32x4 v = { (p + 0 == c) ? 1.f : 0.f, (p + 1 == c) ? 1.f : 0.f,
                    (p + 2 == c) ? 1.f : 0.f, (p + 3 == c) ? 1.f : 0.f };
        __builtin_nontemporal_store(v, body + s);
    }
    if (lane < tail) {
        int p = head + 4 * nb4 + lane;
        out[F + p] = (p == c) ? 1.f : 0.f;
    }
}

__global__ void vq_finalize(const float* __restrict__ partials, float* __restrict__ out) {
    __shared__ float sm[256];
    float a = 0.f;
    for (int i = threadIdx.x; i < 16384; i += 256) a += partials[i];
    sm[threadIdx.x] = a;
    __syncthreads();
    for (int s = 128; s > 0; s >>= 1) {
        if ((int)threadIdx.x < s) sm[threadIdx.x] += sm[threadIdx.x + s];
        __syncthreads();
    }
    if (threadIdx.x == 0) {
        float mean = sm[0] / 8388608.f;
        out[O_LOSS] = 1.25f * mean;
        out[O_PERP] = 0.f;
    }
}

extern "C" void kernel_launch(void* const* d_in, const int* in_sizes, int n_in,
                              void* d_out, int out_size, void* d_ws, size_t ws_size,
                              hipStream_t stream) {
    const float* z   = (const float*)d_in[0];
    const float* emb = (const float*)d_in[1];
    float* out = (float*)d_out;
    float* ws  = (float*)d_ws;

    hipLaunchKernelGGL(prep_embT, dim3(33), dim3(256), 0, stream, emb, ws);
    hipLaunchKernelGGL(prep_G, dim3(8 * 33), dim3(256), 0, stream, emb, ws);
    hipLaunchKernelGGL(vq_main, dim3(4096), dim3(256), 0, stream, z, emb, ws, out);
    hipLaunchKernelGGL(onehot_write, dim3((BTOT * NSUB) / 4), dim3(256), 0, stream, out);
    hipLaunchKernelGGL(vq_finalize, dim3(1), dim3(256), 0, stream, ws + OFF_PART, out);
}

// Round 7
// 911.960 us; speedup vs baseline: 1.5815x; 1.3986x over previous
//
#include <hip/hip_runtime.h>
#include <cstdint>

#define NSUB 8
#define KC   1024
#define KP   1025
#define KPAD 1028      // padded row length (16B-aligned float4 rows)
#define EDIM 64
#define BTOT 16384
#define DHID 512
#define NDEPTH 4
#define MARGIN 1e-3f   // fp32 gap below which we re-resolve via np-key emulation
#define NBW   4        // rows per wave
#define NBB   16       // rows per block (4 waves)
#define NBLK  (BTOT / NBB * NSUB)   // 8192 blocks

typedef float f32x4 __attribute__((ext_vector_type(4)));

// ---- workspace layout (floats) ----
#define OFF_EMBT 0u                      // [8][64][1028], pre-scaled by -2
#define OFF_ESQ  526336u                 // [8][1028]
#define OFF_G2   534560u                 // [8][1025][1028] = 2*<e_c,e_k>
#define OFF_PART 8964160u                // [8192] per-block loss partials

// ---- output layout (floats, concatenated in return order) ----
#define O_LOSS 0
#define O_ZQ   1ull
#define O_PERP 8388609ull
#define O_ENC  8388610ull
#define O_IDX  142737410ull

// numpy SSE2 pairwise sum of 64 fp32 squares (bit-matches np.sum(x*x, -1)).
__device__ __forceinline__ float np_pairwise_sq64(const float* a) {
    float r[8];
    #pragma unroll
    for (int j = 0; j < 8; ++j) r[j] = __fmul_rn(a[j], a[j]);
    #pragma unroll
    for (int t = 1; t < 8; ++t)
        #pragma unroll
        for (int j = 0; j < 8; ++j)
            r[j] = __fadd_rn(r[j], __fmul_rn(a[8 * t + j], a[8 * t + j]));
    float u0 = __fadd_rn(r[0], r[4]), u1 = __fadd_rn(r[1], r[5]);
    float u2 = __fadd_rn(r[2], r[6]), u3 = __fadd_rn(r[3], r[7]);
    return __fadd_rn(__fadd_rn(u0, u1), __fadd_rn(u2, u3));
}

__global__ void prep_embT(const float* __restrict__ emb, float* __restrict__ ws) {
    int t = blockIdx.x * 256 + threadIdx.x;
    if (t >= NSUB * KPAD) return;
    int n = t / KPAD, k = t - n * KPAD;
    float* embT = ws + OFF_EMBT + (size_t)n * EDIM * KPAD;
    float es = 0.f;
    if (k >= 1 && k <= KC) {
        const float* row = emb + ((size_t)n * KC + (k - 1)) * EDIM;
        float a[EDIM];
        #pragma unroll
        for (int e = 0; e < EDIM; ++e) {
            a[e] = row[e];
            embT[(size_t)e * KPAD + k] = -2.f * a[e];   // exact (exponent shift)
        }
        es = np_pairwise_sq64(a);
    } else {
        #pragma unroll
        for (int e = 0; e < EDIM; ++e) embT[(size_t)e * KPAD + k] = 0.f;
    }
    ws[OFF_ESQ + (size_t)n * KPAD + k] = es;
}

__global__ void prep_G(const float* __restrict__ emb, float* __restrict__ ws) {
    __shared__ float A[32][EDIM];
    int n  = blockIdx.x & 7;
    int c0 = (blockIdx.x >> 3) * 32;
    for (int idx = threadIdx.x; idx < 32 * EDIM; idx += 256) {
        int ci = idx >> 6, e = idx & 63, c = c0 + ci;
        float v = 0.f;
        if (c >= 1 && c <= KC) v = emb[((size_t)n * KC + (c - 1)) * EDIM + e];
        A[ci][e] = v;
    }
    __syncthreads();
    float* G2 = ws + OFF_G2 + (size_t)n * KP * KPAD;
    for (int k = threadIdx.x; k <= KC; k += 256) {
        float4 B4[16];
        if (k >= 1) {
            const float4* row = (const float4*)(emb + ((size_t)n * KC + (k - 1)) * EDIM);
            #pragma unroll
            for (int q = 0; q < 16; ++q) B4[q] = row[q];
        } else {
            #pragma unroll
            for (int q = 0; q < 16; ++q) B4[q] = make_float4(0.f, 0.f, 0.f, 0.f);
        }
        for (int ci = 0; ci < 32; ++ci) {
            int c = c0 + ci;
            if (c > KC) break;
            float s = 0.f;
            #pragma unroll
            for (int q = 0; q < 16; ++q) {
                s = fmaf(A[ci][4 * q + 0], B4[q].x, s);
                s = fmaf(A[ci][4 * q + 1], B4[q].y, s);
                s = fmaf(A[ci][4 * q + 2], B4[q].z, s);
                s = fmaf(A[ci][4 * q + 3], B4[q].w, s);
            }
            G2[(size_t)c * KPAD + k] = s + s;
        }
    }
}

// Main fused kernel: 4 waves/block; wave handles 4 b-rows for one n.
// acc[4][4] f32x4 = 64 VGPRs of register-resident scores; no spill at 128 cap.
__global__ void __launch_bounds__(256, 4) vq_main(
    const float* __restrict__ z, const float* __restrict__ emb,
    float* __restrict__ ws, float* __restrict__ out)
{
    __shared__ __align__(16) float zt[NBB][EDIM];
    __shared__ __align__(16) float eT[8 * KPAD];
    __shared__ float zres_sh[4][EDIM];
    __shared__ float lred[4];

    const int n    = blockIdx.x & 7;
    const int b0   = (blockIdx.x >> 3) * NBB;
    const int w    = threadIdx.x >> 6;
    const int lane = threadIdx.x & 63;

    for (int idx = threadIdx.x; idx < NBB * EDIM; idx += 256) {
        int i = idx >> 6, e = idx & 63;
        zt[i][e] = z[(size_t)(b0 + i) * DHID + n * EDIM + e];
    }

    const float* __restrict__ esq = ws + OFF_ESQ + (size_t)n * KPAD;
    f32x4 acc[NBW][4];
    float s1024[NBW], zq[NBW], zres_f[NBW];
    {
        f32x4 e4[4];
        #pragma unroll
        for (int j = 0; j < 4; ++j)
            e4[j] = *(const f32x4*)(esq + j * 256 + 4 * lane);
        float es24 = esq[KC];
        #pragma unroll
        for (int i = 0; i < NBW; ++i) {
            #pragma unroll
            for (int j = 0; j < 4; ++j) acc[i][j] = e4[j];
            s1024[i] = es24;
            zq[i] = 0.f;
        }
    }

    // depth-0: score_k = e_sq[k] + sum_e z[e] * (-2*emb[e][k])
    const float* __restrict__ embTn = ws + OFF_EMBT + (size_t)n * EDIM * KPAD;
    for (int ec = 0; ec < EDIM; ec += 8) {
        __syncthreads();
        {
            const f32x4* src = (const f32x4*)(embTn + (size_t)ec * KPAD);
            f32x4* dst = (f32x4*)eT;
            for (int idx = threadIdx.x; idx < 8 * KPAD / 4; idx += 256)
                dst[idx] = src[idx];
        }
        __syncthreads();
        #pragma unroll
        for (int e8 = 0; e8 < 8; ++e8) {
            float zb[NBW];
            #pragma unroll
            for (int i = 0; i < NBW; ++i) zb[i] = zt[(w << 2) + i][ec + e8];
            float ev24 = eT[e8 * KPAD + KC];
            #pragma unroll
            for (int j = 0; j < 4; ++j) {
                f32x4 ev = *(const f32x4*)(eT + e8 * KPAD + j * 256 + 4 * lane);
                #pragma unroll
                for (int i = 0; i < NBW; ++i) {
                    acc[i][j].x = fmaf(zb[i], ev.x, acc[i][j].x);
                    acc[i][j].y = fmaf(zb[i], ev.y, acc[i][j].y);
                    acc[i][j].z = fmaf(zb[i], ev.z, acc[i][j].z);
                    acc[i][j].w = fmaf(zb[i], ev.w, acc[i][j].w);
                }
            }
            #pragma unroll
            for (int i = 0; i < NBW; ++i) s1024[i] = fmaf(zb[i], ev24, s1024[i]);
        }
    }

    #pragma unroll
    for (int i = 0; i < NBW; ++i) zres_f[i] = zt[(w << 2) + i][lane];

    const float* __restrict__ G2n = ws + OFF_G2 + (size_t)n * KP * KPAD;
    int idxf[NBW];
    for (int d = 0; d < NDEPTH; ++d) {
        #pragma unroll
        for (int i = 0; i < NBW; ++i) {
            // local scan: min + lowest-index over this lane's 17 slots
            float bv = 3.402823466e38f;
            int bk = 0;
            #pragma unroll
            for (int j = 0; j < 4; ++j) {
                int kb = j * 256 + (lane << 2);
                f32x4 a = acc[i][j];
                if (a.x < bv) { bv = a.x; bk = kb; }
                if (a.y < bv) { bv = a.y; bk = kb + 1; }
                if (a.z < bv) { bv = a.z; bk = kb + 2; }
                if (a.w < bv) { bv = a.w; bk = kb + 3; }
            }
            if (s1024[i] < bv) { bv = s1024[i]; bk = KC; }
            // wave argmin with lowest-index tie-break (== jnp.argmin)
            #pragma unroll
            for (int off = 32; off >= 1; off >>= 1) {
                float ov = __shfl_xor(bv, off, 64);
                int   ok = __shfl_xor(bk, off, 64);
                if (ov < bv || (ov == bv && ok < bk)) { bv = ov; bk = ok; }
            }
            // candidate mask: all slots within MARGIN of the global min
            float thr = __fadd_rn(bv, MARGIN);
            int m17 = 0;
            #pragma unroll
            for (int j = 0; j < 4; ++j) {
                f32x4 a = acc[i][j];
                if (a.x < thr) m17 |= 1 << (4 * j + 0);
                if (a.y < thr) m17 |= 1 << (4 * j + 1);
                if (a.z < thr) m17 |= 1 << (4 * j + 2);
                if (a.w < thr) m17 |= 1 << (4 * j + 3);
            }
            if (lane == 0 && s1024[i] < thr) m17 |= 1 << 16;
            unsigned long long lmask = __ballot(m17 != 0);
            bool multi = (__popcll(lmask) > 1) || __any(__popc(m17) > 1);
            float zres_val = zres_f[i];   // scalar only inside resolve
            // ambiguous (rare, wave-uniform): recheck candidates with numpy's
            // exact fp32 key: key_k = fl(fl(A32 - fl(2*B32_k)) + esq32_k)
            if (multi) {
                zres_sh[w][lane] = zres_val;
                asm volatile("s_waitcnt lgkmcnt(0)" ::: "memory");
                float r8[8];
                #pragma unroll
                for (int j = 0; j < 8; ++j)
                    r8[j] = __fmul_rn(zres_sh[w][j], zres_sh[w][j]);
                #pragma unroll
                for (int t2 = 1; t2 < 8; ++t2)
                    #pragma unroll
                    for (int j = 0; j < 8; ++j) {
                        float v = zres_sh[w][8 * t2 + j];
                        r8[j] = __fadd_rn(r8[j], __fmul_rn(v, v));
                    }
                float A32 = __fadd_rn(__fadd_rn(__fadd_rn(r8[0], r8[4]), __fadd_rn(r8[1], r8[5])),
                                      __fadd_rn(__fadd_rn(r8[2], r8[6]), __fadd_rn(r8[3], r8[7])));
                float bestkey = 3.402823466e38f;
                int bkk = 1 << 30;
                unsigned long long mm = lmask;
                while (mm) {
                    int src = __ffsll(mm) - 1;
                    mm &= mm - 1;
                    int sm = __shfl(m17, src, 64);
                    while (sm) {
                        int bit = __ffs(sm) - 1;
                        sm &= sm - 1;
                        int k = (bit == 16) ? KC : ((bit >> 2) * 256 + (src << 2) + (bit & 3));
                        float key;
                        if (k == 0) {
                            key = A32;
                        } else {
                            // cooperative exact dot: coalesced row load, fp64 butterfly
                            double p = (double)emb[((size_t)n * KC + (k - 1)) * EDIM + lane]
                                     * (double)zres_val;
                            #pragma unroll
                            for (int off = 32; off >= 1; off >>= 1)
                                p += __shfl_xor(p, off, 64);
                            float B32  = (float)p;
                            float twoB = __fmul_rn(2.0f, B32);
                            key = __fadd_rn(__fsub_rn(A32, twoB), esq[k]);
                        }
                        if (key < bestkey || (key == bestkey && k < bkk)) {
                            bestkey = key; bkk = k;
                        }
                    }
                }
                bk = bkk;
            }
            idxf[i] = bk;
            float q = 0.f;
            if (bk > 0)   // wave-uniform branch
                q = emb[((size_t)n * KC + (bk - 1)) * EDIM + lane];
            zq[i] += q;
            zres_f[i] = zres_val - q;   // matches reference's fp32 z_res update
            if (d < NDEPTH - 1) {
                const float* grow = G2n + (size_t)bk * KPAD;
                #pragma unroll
                for (int j = 0; j < 4; ++j) {
                    f32x4 g = *(const f32x4*)(grow + j * 256 + 4 * lane);
                    acc[i][j].x += g.x; acc[i][j].y += g.y;
                    acc[i][j].z += g.z; acc[i][j].w += g.w;
                }
                s1024[i] += grow[KC];
            }
        }
    }

    // outputs: z_q_st, loss partial, indices (one-hot done by onehot_write)
    float lsum = 0.f;
    #pragma unroll
    for (int i = 0; i < NBW; ++i) {
        int b = b0 + (w << 2) + i;
        float zv = zt[(w << 2) + i][lane];
        float t = zq[i] - zv;
        __builtin_nontemporal_store(zv + t, &out[O_ZQ + (size_t)b * DHID + n * EDIM + lane]);
        lsum = fmaf(t, t, lsum);
    }
    #pragma unroll
    for (int off = 32; off >= 1; off >>= 1) lsum += __shfl_xor(lsum, off, 64);
    if (lane == 0) lred[w] = lsum;
    __syncthreads();
    if (threadIdx.x == 0)
        ws[OFF_PART + blockIdx.x] = ((lred[0] + lred[1]) + (lred[2] + lred[3]));

    #pragma unroll
    for (int i = 0; i < NBW; ++i) {
        int b = b0 + (w << 2) + i;
        if (lane == i) out[O_IDX + (size_t)b * NSUB + n] = (float)idxf[i];
    }
}

// Streaming one-hot writer: one wave per (b,n) row; 16B-aligned nt body stores.
__global__ void onehot_write(float* __restrict__ out) {
    int gwave = (blockIdx.x * 256 + threadIdx.x) >> 6;
    int lane  = threadIdx.x & 63;
    if (gwave >= BTOT * NSUB) return;
    int r = gwave;
    int c = (int)out[O_IDX + r];               // written by vq_main earlier in stream
    size_t F = O_ENC + (size_t)r * KP;         // row base (float index)
    int head = (4 - (int)(F & 3)) & 3;
    if (lane < head) out[F + lane] = (lane == c) ? 1.f : 0.f;
    int nbody = KP - head;
    int nb4 = nbody >> 2, tail = nbody & 3;
    f32x4* body = (f32x4*)(out + F + head);
    for (int s = lane; s < nb4; s += 64) {
        int p = head + 4 * s;
        f32x4 v = { (p + 0 == c) ? 1.f : 0.f, (p + 1 == c) ? 1.f : 0.f,
                    (p + 2 == c) ? 1.f : 0.f, (p + 3 == c) ? 1.f : 0.f };
        __builtin_nontemporal_store(v, body + s);
    }
    if (lane < tail) {
        int p = head + 4 * nb4 + lane;
        out[F + p] = (p == c) ? 1.f : 0.f;
    }
}

__global__ void vq_finalize(const float* __restrict__ partials, float* __restrict__ out) {
    __shared__ float sm[256];
    float a = 0.f;
    for (int i = threadIdx.x; i < NBLK; i += 256) a += partials[i];
    sm[threadIdx.x] = a;
    __syncthreads();
    for (int s = 128; s > 0; s >>= 1) {
        if ((int)threadIdx.x < s) sm[threadIdx.x] += sm[threadIdx.x + s];
        __syncthreads();
    }
    if (threadIdx.x == 0) {
        float mean = sm[0] / 8388608.f;
        out[O_LOSS] = 1.25f * mean;
        out[O_PERP] = 0.f;
    }
}

extern "C" void kernel_launch(void* const* d_in, const int* in_sizes, int n_in,
                              void* d_out, int out_size, void* d_ws, size_t ws_size,
                              hipStream_t stream) {
    const float* z   = (const float*)d_in[0];
    const float* emb = (const float*)d_in[1];
    float* out = (float*)d_out;
    float* ws  = (float*)d_ws;

    hipLaunchKernelGGL(prep_embT, dim3(33), dim3(256), 0, stream, emb, ws);
    hipLaunchKernelGGL(prep_G, dim3(8 * 33), dim3(256), 0, stream, emb, ws);
    hipLaunchKernelGGL(vq_main, dim3(NBLK), dim3(256), 0, stream, z, emb, ws, out);
    hipLaunchKernelGGL(onehot_write, dim3((BTOT * NSUB) / 4), dim3(256), 0, stream, out);
    hipLaunchKernelGGL(vq_finalize, dim3(1), dim3(256), 0, stream, ws + OFF_PART, out);
}